// Round 14
// baseline (188.222 us; speedup 1.0000x reference)
//
#include <hip/hip_runtime.h>

#define B_  4
#define N_  4096
#define K_  32
#define C_  64
#define DH_ 128
#define PPW 8
#define NBLK 512

typedef _Float16 half2v __attribute__((ext_vector_type(2)));
typedef _Float16 half8  __attribute__((ext_vector_type(8)));
typedef __fp16   fp16x2 __attribute__((ext_vector_type(2)));
typedef float  floatx16 __attribute__((ext_vector_type(16)));
typedef unsigned int uint_t;

union HU { half2v h; uint_t u; };
union HU2 { fp16x2 h; uint_t u; };

__device__ __forceinline__ uint_t pk2(float a, float b) {
    HU2 x; x.h = __builtin_amdgcn_cvt_pkrtz(a, b);   // v_cvt_pkrtz_f16_f32
    return x.u;
}

// ---------------------------------------------------------------------------
// Single fused kernel. 512 blocks x 256 thr, __launch_bounds__(256,2):
//  VGPR<=256 & LDS 33.8KB guarantee 2 blocks/CU residency -> all 512 blocks
//  co-resident (256 CUs) -> grid barrier cannot deadlock.
//  Phase 1 = prep (R7 32-pt tiles): QsH/PcatH f16x2 + Bpack + xyz copy.
//  Grid barrier = device-scope atomics + fences (G16).
//  Phase 2 = wave-private main (R13): scalar idx, prefetch-ahead gathers,
//  4 resident B-sets, 32 MFMA/pt, pool identity; then in-wave f-layer.
// ---------------------------------------------------------------------------
__global__ __launch_bounds__(256, 2) void k_fused(
    const float* __restrict__ xyz,
    const float* __restrict__ features,
    const int*   __restrict__ idx,
    const float* __restrict__ W_gv,
    const float* __restrict__ W_gu,
    const float* __restrict__ s_gu, const float* __restrict__ b_gu,
    const float* __restrict__ s_gv, const float* __restrict__ b_gv,
    const float* __restrict__ W_h,  const float* __restrict__ s_h,
    const float* __restrict__ b_h,
    const float* __restrict__ W_f,
    const float* __restrict__ s_f,  const float* __restrict__ b_f,
    float* __restrict__ out_xyz,
    _Float16* __restrict__ Bpack,
    uint_t* __restrict__ QsH,
    uint_t* __restrict__ PcatH,
    uint_t* __restrict__ ctr,
    float* __restrict__ outF)
{
    __shared__ __align__(16) uint_t sh[8448];   // 33792 B, phase-aliased
    const int t   = threadIdx.x;
    const int blk = blockIdx.x;

    // ==================== PHASE 1: prep (32-pt tile) ====================
    {
        const int b  = blk >> 7;
        const int n0 = (blk & 127) * 32;
        float* ftile = (float*)sh;              // 64*33 floats
        float* wtile = (float*)sh + 64*33;      // 64*68 floats

        // side job A: xyz copy (output 0). 512*96 = 49152.
        if (t < 96) { int e = blk*96 + t; out_xyz[e] = xyz[e]; }
        // side job B: Bpack = (W_h*s_h) f16, MFMA B-frag order. 512*32.
        if (t >= 128 && t < 160) {
            int e = blk*32 + (t - 128);
            int j = e & 7, l = (e >> 3) & 63, c = (e >> 9) & 7, ob = e >> 12;
            int o = ob*32 + (l & 31);
            int i = c*16 + (l >> 5)*8 + j;
            Bpack[e] = (_Float16)(W_h[o*DH_ + i] * s_h[o]);
        }

#pragma unroll
        for (int r = 0; r < 2; r++) {    // features tile: 64c x 32n
            const int i4 = r*256 + t, c = i4 >> 3, nq = i4 & 7;
            const float4 f4 = *(const float4*)&features[(b*C_ + c)*N_ + n0 + nq*4];
            ftile[c*33 + nq*4 + 0] = f4.x;
            ftile[c*33 + nq*4 + 1] = f4.y;
            ftile[c*33 + nq*4 + 2] = f4.z;
            ftile[c*33 + nq*4 + 3] = f4.w;
        }
#pragma unroll
        for (int r = 0; r < 4; r++) {    // W_gv transposed: [c][o]
            const int e4 = r*256 + t, o = e4 >> 4, c0 = (e4 & 15)*4;
            const float4 w4 = *(const float4*)&W_gv[o*C_ + c0];
            wtile[(c0+0)*68 + o] = w4.x;
            wtile[(c0+1)*68 + o] = w4.y;
            wtile[(c0+2)*68 + o] = w4.z;
            wtile[(c0+3)*68 + o] = w4.w;
        }
        __syncthreads();

        const int n  = t >> 3;       // 0..31
        const int og = t & 7;        // o-chunk of 8
        const int o0 = og * 8;

        float acc[8] = {};
        for (int c = 0; c < 64; c++) {
            const float a = ftile[c*33 + n];
            float wv[8];
            *(float4*)&wv[0] = *(const float4*)&wtile[c*68 + o0];
            *(float4*)&wv[4] = *(const float4*)&wtile[c*68 + o0 + 4];
#pragma unroll
            for (int oo = 0; oo < 8; oo++)
                acc[oo] = fmaf(a, wv[oo], acc[oo]);
        }

        const int bn = b*N_ + n0 + n;
        const float x0 = xyz[bn*3+0], x1 = xyz[bn*3+1], x2 = xyz[bn*3+2];

        float sgu[8], bgu[8], sgv[8], bgv[8];
        *(float4*)&sgu[0] = *(const float4*)&s_gu[o0]; *(float4*)&sgu[4] = *(const float4*)&s_gu[o0+4];
        *(float4*)&bgu[0] = *(const float4*)&b_gu[o0]; *(float4*)&bgu[4] = *(const float4*)&b_gu[o0+4];
        *(float4*)&sgv[0] = *(const float4*)&s_gv[o0]; *(float4*)&sgv[4] = *(const float4*)&s_gv[o0+4];
        *(float4*)&bgv[0] = *(const float4*)&b_gv[o0]; *(float4*)&bgv[4] = *(const float4*)&b_gv[o0+4];

        float qv[8], rv[8];
#pragma unroll
        for (int oo = 0; oo < 8; oo++) {
            const int o = o0 + oo;
            qv[oo] = x0*W_gu[o*6+0] + x1*W_gu[o*6+1] + x2*W_gu[o*6+2];
            rv[oo] = x0*W_gu[o*6+3] + x1*W_gu[o*6+4] + x2*W_gu[o*6+5];
        }
        uint4 qa, pa;
        qa.x = pk2(qv[0]*sgu[0]+bgu[0], qv[1]*sgu[1]+bgu[1]);
        qa.y = pk2(qv[2]*sgu[2]+bgu[2], qv[3]*sgu[3]+bgu[3]);
        qa.z = pk2(qv[4]*sgu[4]+bgu[4], qv[5]*sgu[5]+bgu[5]);
        qa.w = pk2(qv[6]*sgu[6]+bgu[6], qv[7]*sgu[7]+bgu[7]);
        pa.x = pk2(rv[0]*sgu[0], rv[1]*sgu[1]);
        pa.y = pk2(rv[2]*sgu[2], rv[3]*sgu[3]);
        pa.z = pk2(rv[4]*sgu[4], rv[5]*sgu[5]);
        pa.w = pk2(rv[6]*sgu[6], rv[7]*sgu[7]);
        *(uint4*)&QsH  [bn*64 + og*4] = qa;
        *(uint4*)&PcatH[bn*64 + og*4] = pa;
        qa.x = pk2(acc[0]*sgv[0]+bgv[0], acc[1]*sgv[1]+bgv[1]);
        qa.y = pk2(acc[2]*sgv[2]+bgv[2], acc[3]*sgv[3]+bgv[3]);
        qa.z = pk2(acc[4]*sgv[4]+bgv[4], acc[5]*sgv[5]+bgv[5]);
        qa.w = pk2(acc[6]*sgv[6]+bgv[6], acc[7]*sgv[7]+bgv[7]);
        pa.x = pk2(acc[0]*sgv[0], acc[1]*sgv[1]);
        pa.y = pk2(acc[2]*sgv[2], acc[3]*sgv[3]);
        pa.z = pk2(acc[4]*sgv[4], acc[5]*sgv[5]);
        pa.w = pk2(acc[6]*sgv[6], acc[7]*sgv[7]);
        *(uint4*)&QsH  [bn*64 + 32 + og*4] = qa;
        *(uint4*)&PcatH[bn*64 + 32 + og*4] = pa;
    }

    // ==================== GRID BARRIER (device scope) ====================
    __syncthreads();
    if (t == 0) {
        __threadfence();                       // release: publish P1 writes
        atomicAdd(ctr, 1u);
        while (__hip_atomic_load(ctr, __ATOMIC_RELAXED,
                                 __HIP_MEMORY_SCOPE_AGENT) < (uint_t)NBLK)
            __builtin_amdgcn_s_sleep(2);
    }
    __syncthreads();
    __threadfence();                           // acquire: see all P1 writes

    // ==================== PHASE 2: wave-private main ====================
    const int wq   = __builtin_amdgcn_readfirstlane(t >> 6);
    const int lane = t & 63;
    const int m    = lane & 31;
    const int hh   = lane >> 5;
    uint_t* fuse = sh + wq*2112;               // wave-private 8448 B

    half8 Bf[4][8];
#pragma unroll
    for (int ob = 0; ob < 4; ob++)
#pragma unroll
        for (int c = 0; c < 8; c++)
            Bf[ob][c] = *(const half8*)&Bpack[((ob*8 + c)*64 + lane)*8];

    float nbh[4], b32[4];
#pragma unroll
    for (int ob = 0; ob < 4; ob++) {
        const float bh = b_h[ob*32 + m];
        nbh[ob] = -bh;
        b32[ob] = 32.f * bh;
    }

    const int gw    = blk*4 + wq;
    const int bnb   = gw * PPW;
    const int base0 = bnb & ~(N_ - 1);         // b*N_

    uint_t pg[32];
    uint_t qw;
    float  pool_r[PPW][4];                     // valid on hh==0 lanes

    // prologue: scalar idx row p0, 32 coalesced row-gathers, build fuse
    {
        const int* ip = idx + (bnb & (N_-1))*K_;     // uniform -> s_load
        int js[32];
#pragma unroll
        for (int it = 0; it < 32; it++) js[it] = ip[it];
        qw = QsH[(size_t)bnb*64 + lane];
#pragma unroll
        for (int it = 0; it < 32; it++)
            pg[it] = PcatH[((size_t)(base0 + js[it]) << 6) + lane];
#pragma unroll
        for (int it = 0; it < 32; it++) {
            HU a, pv; a.u = qw; pv.u = pg[it];
            half2v v = a.h + pv.h;
            HU o2; o2.h = __builtin_elementwise_max(v, (half2v){(_Float16)0.f,(_Float16)0.f});
            fuse[it*66 + lane] = o2.u;
        }
    }

#pragma unroll
    for (int p = 0; p < PPW; p++) {
        // A: prefetch point p+1
        uint_t qw_n = 0;
        if (p + 1 < PPW) {
            const int* ip = idx + ((bnb + p + 1) & (N_-1))*K_;   // s_load
            int js[32];
#pragma unroll
            for (int it = 0; it < 32; it++) js[it] = ip[it];
            qw_n = QsH[(size_t)(bnb + p + 1)*64 + lane];
#pragma unroll
            for (int it = 0; it < 32; it++)
                pg[it] = PcatH[((size_t)(base0 + js[it]) << 6) + lane];
        }

        // B: 16 ds_read_b64 feed 32 MFMAs (4 o-sets)
        floatx16 acc0 = {}, acc1 = {}, acc2 = {}, acc3 = {};
#pragma unroll
        for (int c = 0; c < 8; c++) {
            const int wb = m*66 + c*8 + hh*4;
            union { uint_t u[4]; half8 h; } av;
            *(uint2*)&av.u[0] = *(const uint2*)&fuse[wb];
            *(uint2*)&av.u[2] = *(const uint2*)&fuse[wb + 2];
            acc0 = __builtin_amdgcn_mfma_f32_32x32x16_f16(av.h, Bf[0][c], acc0, 0, 0, 0);
            acc1 = __builtin_amdgcn_mfma_f32_32x32x16_f16(av.h, Bf[1][c], acc1, 0, 0, 0);
            acc2 = __builtin_amdgcn_mfma_f32_32x32x16_f16(av.h, Bf[2][c], acc2, 0, 0, 0);
            acc3 = __builtin_amdgcn_mfma_f32_32x32x16_f16(av.h, Bf[3][c], acc3, 0, 0, 0);
        }

        // pool: sum max(x,-b), fold halves, +32b; keep in registers
        float v0 = 0.f, v1 = 0.f, v2 = 0.f, v3 = 0.f;
#pragma unroll
        for (int rg = 0; rg < 16; rg++) {
            v0 += fmaxf(acc0[rg], nbh[0]);
            v1 += fmaxf(acc1[rg], nbh[1]);
            v2 += fmaxf(acc2[rg], nbh[2]);
            v3 += fmaxf(acc3[rg], nbh[3]);
        }
        v0 += __shfl_xor(v0, 32);
        v1 += __shfl_xor(v1, 32);
        v2 += __shfl_xor(v2, 32);
        v3 += __shfl_xor(v3, 32);
        pool_r[p][0] = v0 + b32[0];
        pool_r[p][1] = v1 + b32[1];
        pool_r[p][2] = v2 + b32[2];
        pool_r[p][3] = v3 + b32[3];

        // C: build fuse for p+1 (wave-private DS in-order => safe)
        if (p + 1 < PPW) {
#pragma unroll
            for (int it = 0; it < 32; it++) {
                HU a, pv; a.u = qw_n; pv.u = pg[it];
                half2v v = a.h + pv.h;
                HU o2; o2.h = __builtin_elementwise_max(v, (half2v){(_Float16)0.f,(_Float16)0.f});
                fuse[it*66 + lane] = o2.u;
            }
        }
    }

    // ---- in-wave f layer + residual (fuse region now free -> pooled) ----
    float* poolL = (float*)fuse;               // [p][i], stride 132
    if (hh == 0) {
#pragma unroll
        for (int p = 0; p < PPW; p++) {
            poolL[p*132 +  0 + m] = pool_r[p][0];
            poolL[p*132 + 32 + m] = pool_r[p][1];
            poolL[p*132 + 64 + m] = pool_r[p][2];
            poolL[p*132 + 96 + m] = pool_r[p][3];
        }
    }
    // per-wave DS in-order; compiler inserts lgkmcnt before dependent reads

    const int b  = bnb >> 12;
    const int n0 = bnb & (N_ - 1);
    const int c  = lane;

    float accf[PPW] = {};
    for (int i0 = 0; i0 < DH_; i0 += 4) {
        const float4 wv = *(const float4*)&W_f[c*DH_ + i0];
#pragma unroll
        for (int p = 0; p < PPW; p++) {
            const float4 p4 = *(const float4*)&poolL[p*132 + i0];   // broadcast
            accf[p] += wv.x*p4.x + wv.y*p4.y + wv.z*p4.z + wv.w*p4.w;
        }
    }
    const float sfc = s_f[c] * (1.f/(float)K_);
    const float bfc = b_f[c];
    const float4 fr0 = *(const float4*)&features[(b*C_ + c)*N_ + n0];
    const float4 fr1 = *(const float4*)&features[(b*C_ + c)*N_ + n0 + 4];
    float4 ov0, ov1;
    ov0.x = fmaxf(accf[0]*sfc + bfc, 0.f) + fr0.x;
    ov0.y = fmaxf(accf[1]*sfc + bfc, 0.f) + fr0.y;
    ov0.z = fmaxf(accf[2]*sfc + bfc, 0.f) + fr0.z;
    ov0.w = fmaxf(accf[3]*sfc + bfc, 0.f) + fr0.w;
    ov1.x = fmaxf(accf[4]*sfc + bfc, 0.f) + fr1.x;
    ov1.y = fmaxf(accf[5]*sfc + bfc, 0.f) + fr1.y;
    ov1.z = fmaxf(accf[6]*sfc + bfc, 0.f) + fr1.z;
    ov1.w = fmaxf(accf[7]*sfc + bfc, 0.f) + fr1.w;
    *(float4*)&outF[(b*C_ + c)*N_ + n0]     = ov0;
    *(float4*)&outF[(b*C_ + c)*N_ + n0 + 4] = ov1;
}

// ---------------------------------------------------------------------------
extern "C" void kernel_launch(void* const* d_in, const int* in_sizes, int n_in,
                              void* d_out, int out_size, void* d_ws, size_t ws_size,
                              hipStream_t stream)
{
    const float* xyz      = (const float*)d_in[0];
    const float* features = (const float*)d_in[1];
    const int*   idx      = (const int*)  d_in[2];
    const float* W_gu     = (const float*)d_in[3];
    const float* s_gu     = (const float*)d_in[4];
    const float* b_gu     = (const float*)d_in[5];
    const float* W_gv     = (const float*)d_in[6];
    const float* s_gv     = (const float*)d_in[7];
    const float* b_gv     = (const float*)d_in[8];
    const float* W_h      = (const float*)d_in[9];
    const float* s_h      = (const float*)d_in[10];
    const float* b_h      = (const float*)d_in[11];
    const float* W_f      = (const float*)d_in[12];
    const float* s_f      = (const float*)d_in[13];
    const float* b_f      = (const float*)d_in[14];

    float* out  = (float*)d_out;          // tuple: xyz first, then out
    float* outF = out + B_*N_*3;

    // workspace carve (~8.1 MB)
    char* wp = (char*)d_ws;
    uint_t*   QsH   = (uint_t*)wp;   wp += (size_t)B_*N_*64*4;    // 4 MB
    uint_t*   PcatH = (uint_t*)wp;   wp += (size_t)B_*N_*64*4;    // 4 MB
    _Float16* Bpack = (_Float16*)wp; wp += DH_*DH_*2;             // 32 KB
    uint_t*   ctr   = (uint_t*)wp;   wp += 64;

    hipMemsetAsync((void*)ctr, 0, 4, stream);   // captured: re-zeroed per replay
    k_fused<<<NBLK, 256, 0, stream>>>(xyz, features, idx, W_gv, W_gu,
                                      s_gu, b_gu, s_gv, b_gv, W_h, s_h, b_h,
                                      W_f, s_f, b_f,
                                      out, Bpack, QsH, PcatH, ctr, outF);
}

// Round 15
// 130.545 us; speedup vs baseline: 1.4418x; 1.4418x over previous
//
#include <hip/hip_runtime.h>

#define B_  4
#define N_  4096
#define K_  32
#define C_  64
#define DH_ 128
#define PPW 8

typedef _Float16 half2v __attribute__((ext_vector_type(2)));
typedef _Float16 half8  __attribute__((ext_vector_type(8)));
typedef __fp16   fp16x2 __attribute__((ext_vector_type(2)));
typedef float  floatx16 __attribute__((ext_vector_type(16)));
typedef unsigned int uint_t;

union HU { half2v h; uint_t u; };
union HU2 { fp16x2 h; uint_t u; };

__device__ __forceinline__ uint_t pk2(float a, float b) {
    HU2 x; x.h = __builtin_amdgcn_cvt_pkrtz(a, b);   // v_cvt_pkrtz_f16_f32
    return x.u;
}

// ---------------------------------------------------------------------------
// Kernel 1: prep. 1024 blocks x 256 thr; block = (b = blk>>8, 16-pt tile).
// ---------------------------------------------------------------------------
__global__ __launch_bounds__(256) void k_prep(
    const float* __restrict__ xyz,
    const float* __restrict__ features,
    const float* __restrict__ W_gv,
    const float* __restrict__ W_gu,
    const float* __restrict__ s_gu, const float* __restrict__ b_gu,
    const float* __restrict__ s_gv, const float* __restrict__ b_gv,
    const float* __restrict__ W_h,  const float* __restrict__ s_h,
    float* __restrict__ out_xyz,
    _Float16* __restrict__ Bpack,
    uint_t* __restrict__ QsH,
    uint_t* __restrict__ PcatH)
{
    const int blk = blockIdx.x;
    const int b   = blk >> 8;
    const int n0  = (blk & 255) * 16;
    const int t   = threadIdx.x;

    if (t < 48) { int e = blk*48 + t; out_xyz[e] = xyz[e]; }
    if (t >= 64 && t < 80) {
        int e = blk*16 + (t - 64);
        int j = e & 7, l = (e >> 3) & 63, c = (e >> 9) & 7, ob = e >> 12;
        int o = ob*32 + (l & 31);
        int i = c*16 + (l >> 5)*8 + j;
        Bpack[e] = (_Float16)(W_h[o*DH_ + i] * s_h[o]);
    }

    __shared__ __align__(16) float ftile[64 * 17];   // [c][n], stride 17
    __shared__ __align__(16) float wtile[64 * 68];   // [c][o], stride 68

    {
        const int c = t >> 2, nq = t & 3;
        const float4 f4 = *(const float4*)&features[(b*C_ + c)*N_ + n0 + nq*4];
        ftile[c*17 + nq*4 + 0] = f4.x;
        ftile[c*17 + nq*4 + 1] = f4.y;
        ftile[c*17 + nq*4 + 2] = f4.z;
        ftile[c*17 + nq*4 + 3] = f4.w;
    }
#pragma unroll
    for (int r = 0; r < 4; r++) {
        const int e4 = r*256 + t, o = e4 >> 4, c0 = (e4 & 15)*4;
        const float4 w4 = *(const float4*)&W_gv[o*C_ + c0];
        wtile[(c0+0)*68 + o] = w4.x;
        wtile[(c0+1)*68 + o] = w4.y;
        wtile[(c0+2)*68 + o] = w4.z;
        wtile[(c0+3)*68 + o] = w4.w;
    }
    __syncthreads();

    const int n  = t >> 4;
    const int oq = t & 15;
    const int o0 = oq * 4;

    float acc[4] = {};
#pragma unroll 4
    for (int c = 0; c < 64; c++) {
        const float a = ftile[c*17 + n];
        const float4 wv = *(const float4*)&wtile[c*68 + o0];
        acc[0] = fmaf(a, wv.x, acc[0]);
        acc[1] = fmaf(a, wv.y, acc[1]);
        acc[2] = fmaf(a, wv.z, acc[2]);
        acc[3] = fmaf(a, wv.w, acc[3]);
    }

    const int bn = b*N_ + n0 + n;
    const float x0 = xyz[bn*3+0], x1 = xyz[bn*3+1], x2 = xyz[bn*3+2];

    const float4 sgu = *(const float4*)&s_gu[o0];
    const float4 bgu = *(const float4*)&b_gu[o0];
    const float4 sgv = *(const float4*)&s_gv[o0];
    const float4 bgv = *(const float4*)&b_gv[o0];

    float q[4], r[4];
#pragma unroll
    for (int jj = 0; jj < 4; jj++) {
        const int o = o0 + jj;
        q[jj] = x0*W_gu[o*6+0] + x1*W_gu[o*6+1] + x2*W_gu[o*6+2];
        r[jj] = x0*W_gu[o*6+3] + x1*W_gu[o*6+4] + x2*W_gu[o*6+5];
    }
    uint2 qa, pa;
    qa.x = pk2(q[0]*sgu.x+bgu.x, q[1]*sgu.y+bgu.y);
    qa.y = pk2(q[2]*sgu.z+bgu.z, q[3]*sgu.w+bgu.w);
    pa.x = pk2(r[0]*sgu.x, r[1]*sgu.y);
    pa.y = pk2(r[2]*sgu.z, r[3]*sgu.w);
    *(uint2*)&QsH  [bn*64 + oq*2] = qa;
    *(uint2*)&PcatH[bn*64 + oq*2] = pa;
    qa.x = pk2(acc[0]*sgv.x+bgv.x, acc[1]*sgv.y+bgv.y);
    qa.y = pk2(acc[2]*sgv.z+bgv.z, acc[3]*sgv.w+bgv.w);
    pa.x = pk2(acc[0]*sgv.x, acc[1]*sgv.y);
    pa.y = pk2(acc[2]*sgv.z, acc[3]*sgv.w);
    *(uint2*)&QsH  [bn*64 + 32 + oq*2] = qa;
    *(uint2*)&PcatH[bn*64 + 32 + oq*2] = pa;
}

// ---------------------------------------------------------------------------
// Kernel 2: fused main + f-layer (R10, best measured). 128 thr = 2 waves.
//  Scalar idx (s_load) -> SGPR row bases; 16 coalesced gathers/wave/pt
//  prefetched one point ahead; double-buffered fuse; one barrier per point.
// ---------------------------------------------------------------------------
__global__ __launch_bounds__(128) void k_main(
    const int*      __restrict__ idx,
    const uint_t*   __restrict__ QsH,
    const uint_t*   __restrict__ PcatH,
    const _Float16* __restrict__ Bpack,
    const float*    __restrict__ b_h,
    const float*    __restrict__ W_f,
    const float*    __restrict__ s_f, const float* __restrict__ b_f,
    const float*    __restrict__ features,
    float* __restrict__ outF)
{
    const int t    = threadIdx.x;
    const int ohu  = __builtin_amdgcn_readfirstlane(t >> 6);   // wave o-half
    const int lane = t & 63;
    const int m    = lane & 31;
    const int hh   = lane >> 5;

    __shared__ uint_t fuse[2][32 * 66];                 // double buffer
    __shared__ __align__(16) float pooled[PPW * 132];

    half8 Bf[2][8];
#pragma unroll
    for (int ob = 0; ob < 2; ob++)
#pragma unroll
        for (int c = 0; c < 8; c++)
            Bf[ob][c] = *(const half8*)&Bpack[(((ohu*2 + ob)*8 + c)*64 + lane)*8];

    const float bh0 = b_h[(ohu*2+0)*32 + m];
    const float bh1 = b_h[(ohu*2+1)*32 + m];

    const int bnb   = blockIdx.x * PPW;
    const int base0 = bnb & ~(N_ - 1);                  // b*N_

    uint_t pg[16];
    uint_t qw;
    int js[16];

    // prologue: scalar idx row for p0, gather p0, build fuse[0]
    {
        const int n0p = bnb & (N_ - 1);
        const int* ip = idx + n0p*K_ + ohu*16;          // uniform -> s_load
#pragma unroll
        for (int it = 0; it < 16; it++) js[it] = ip[it];
        qw = QsH[(size_t)bnb*64 + lane];
#pragma unroll
        for (int it = 0; it < 16; it++)
            pg[it] = PcatH[((size_t)(base0 + js[it]) << 6) + lane];
#pragma unroll
        for (int it = 0; it < 16; it++) {
            HU a, pval; a.u = qw; pval.u = pg[it];
            half2v v = a.h + pval.h;
            HU o2; o2.h = __builtin_elementwise_max(v, (half2v){(_Float16)0.f,(_Float16)0.f});
            fuse[0][(ohu*16 + it)*66 + lane] = o2.u;
        }
    }
    __syncthreads();

#pragma unroll
    for (int p = 0; p < PPW; p++) {
        const int cur = p & 1, nxt = cur ^ 1;

        // ---- A: scalar idx row + gathers for p+1 (land during MFMA) ----
        uint_t qw_n = 0;
        if (p + 1 < PPW) {
            const int np = (bnb + p + 1) & (N_ - 1);
            const int* ip = idx + np*K_ + ohu*16;       // uniform -> s_load
#pragma unroll
            for (int it = 0; it < 16; it++) js[it] = ip[it];
            qw_n = QsH[(size_t)(bnb + p + 1)*64 + lane];
#pragma unroll
            for (int it = 0; it < 16; it++)
                pg[it] = PcatH[((size_t)(base0 + js[it]) << 6) + lane];
        }

        // ---- B: MFMA + pool on fuse[cur] ----
        floatx16 acc0 = {}, acc1 = {};
#pragma unroll
        for (int c = 0; c < 8; c++) {
            const int wb = m*66 + c*8 + hh*4;
            union { uint_t u[4]; half8 h; } av;
            *(uint2*)&av.u[0] = *(const uint2*)&fuse[cur][wb];
            *(uint2*)&av.u[2] = *(const uint2*)&fuse[cur][wb + 2];
            acc0 = __builtin_amdgcn_mfma_f32_32x32x16_f16(av.h, Bf[0][c], acc0, 0, 0, 0);
            acc1 = __builtin_amdgcn_mfma_f32_32x32x16_f16(av.h, Bf[1][c], acc1, 0, 0, 0);
        }
        float v0 = 0.f, v1 = 0.f;
#pragma unroll
        for (int rg = 0; rg < 16; rg++) {
            v0 += fmaxf(acc0[rg] + bh0, 0.f);
            v1 += fmaxf(acc1[rg] + bh1, 0.f);
        }
        v0 += __shfl_xor(v0, 32);
        v1 += __shfl_xor(v1, 32);
        if (hh == 0) {
            pooled[p*132 + (ohu*2+0)*32 + m] = v0;
            pooled[p*132 + (ohu*2+1)*32 + m] = v1;
        }

        // ---- C: build fuse[nxt] from gathered regs ----
        if (p + 1 < PPW) {
#pragma unroll
            for (int it = 0; it < 16; it++) {
                HU a, pval; a.u = qw_n; pval.u = pg[it];
                half2v v = a.h + pval.h;
                HU o2; o2.h = __builtin_elementwise_max(v, (half2v){(_Float16)0.f,(_Float16)0.f});
                fuse[nxt][(ohu*16 + it)*66 + lane] = o2.u;
            }
        }
        // ---- D: one barrier per point ----
        __syncthreads();
    }

    // ---- f layer + residual for the block's 8 points ----
    const int b   = bnb >> 12;
    const int n0  = bnb & (N_ - 1);
    const int c   = t >> 1;      // 0..63
    const int r2  = t & 1;       // 4 n's per thread

    float acc[4] = {};
#pragma unroll 4
    for (int i0 = 0; i0 < DH_; i0 += 4) {
        const float4 wv = *(const float4*)&W_f[c*DH_ + i0];
#pragma unroll
        for (int r = 0; r < 4; r++) {
            const float4 p4 = *(const float4*)&pooled[(r2*4 + r)*132 + i0];
            acc[r] += wv.x*p4.x + wv.y*p4.y + wv.z*p4.z + wv.w*p4.w;
        }
    }
    const float sfc = s_f[c] * (1.f/(float)K_);
    const float bfc = b_f[c];
    const float4 fr = *(const float4*)&features[(b*C_ + c)*N_ + n0 + r2*4];
    float4 ov;
    ov.x = fmaxf(acc[0]*sfc + bfc, 0.f) + fr.x;
    ov.y = fmaxf(acc[1]*sfc + bfc, 0.f) + fr.y;
    ov.z = fmaxf(acc[2]*sfc + bfc, 0.f) + fr.z;
    ov.w = fmaxf(acc[3]*sfc + bfc, 0.f) + fr.w;
    *(float4*)&outF[(b*C_ + c)*N_ + n0 + r2*4] = ov;
}

// ---------------------------------------------------------------------------
extern "C" void kernel_launch(void* const* d_in, const int* in_sizes, int n_in,
                              void* d_out, int out_size, void* d_ws, size_t ws_size,
                              hipStream_t stream)
{
    const float* xyz      = (const float*)d_in[0];
    const float* features = (const float*)d_in[1];
    const int*   idx      = (const int*)  d_in[2];
    const float* W_gu     = (const float*)d_in[3];
    const float* s_gu     = (const float*)d_in[4];
    const float* b_gu     = (const float*)d_in[5];
    const float* W_gv     = (const float*)d_in[6];
    const float* s_gv     = (const float*)d_in[7];
    const float* b_gv     = (const float*)d_in[8];
    const float* W_h      = (const float*)d_in[9];
    const float* s_h      = (const float*)d_in[10];
    const float* b_h      = (const float*)d_in[11];
    const float* W_f      = (const float*)d_in[12];
    const float* s_f      = (const float*)d_in[13];
    const float* b_f      = (const float*)d_in[14];

    float* out  = (float*)d_out;          // tuple: xyz first, then out
    float* outF = out + B_*N_*3;

    // workspace carve (~8.1 MB)
    char* wp = (char*)d_ws;
    uint_t*   QsH   = (uint_t*)wp;   wp += (size_t)B_*N_*64*4;    // 4 MB
    uint_t*   PcatH = (uint_t*)wp;   wp += (size_t)B_*N_*64*4;    // 4 MB
    _Float16* Bpack = (_Float16*)wp; wp += DH_*DH_*2;             // 32 KB

    k_prep<<<B_*(N_/16), 256, 0, stream>>>(xyz, features, W_gv, W_gu,
                                           s_gu, b_gu, s_gv, b_gv, W_h, s_h,
                                           out, Bpack, QsH, PcatH);
    k_main<<<(B_*N_)/PPW, 128, 0, stream>>>(idx, QsH, PcatH, Bpack, b_h,
                                            W_f, s_f, b_f, features, outF);
}